// Round 1
// 1592.000 us; speedup vs baseline: 1.0586x; 1.0586x over previous
//
#include <hip/hip_runtime.h>
#include <math.h>

#define N_NODES 100000
#define N_EDGES 3200000
#define F_IN 256
#define M_OUT 512            // 2*F_OUT concat
#define K_TOT 1024           // [x | Ax | A^2x | A^4x]
#define EPS_BN 1e-3f
#define NUM_CHUNKS 391       // ceil(100000/256) == number of row buckets
#define NB NUM_CHUNKS
#define EPB 16384            // edges per block in scatter pass 1

typedef __attribute__((ext_vector_type(8))) short short8;
typedef __attribute__((ext_vector_type(4))) float floatx4;

__device__ __forceinline__ ushort f2b(float f) {
    union { float f; unsigned u; } c; c.f = f;
    unsigned u = c.u;
    unsigned r = (u + 0x7FFFu + ((u >> 16) & 1u)) >> 16;   // RNE
    return (ushort)r;
}
__device__ __forceinline__ float b2f(ushort b) {
    union { unsigned u; float f; } c; c.u = ((unsigned)b) << 16;
    return c.f;
}

// ---------------- small utility kernels ----------------

__global__ void zero_i32(int* __restrict__ p, int n) {
    int i = blockIdx.x * blockDim.x + threadIdx.x;
    if (i < n) p[i] = 0;
}

__global__ void hist_kernel(const int* __restrict__ row, int* __restrict__ counts, int n) {
    int i = blockIdx.x * blockDim.x + threadIdx.x;
    if (i < n) atomicAdd(&counts[row[i]], 1);
}

__global__ void scan_chunk_sums(const int* __restrict__ counts, int* __restrict__ chunkSums, int n) {
    __shared__ int sm[256];
    int c = blockIdx.x;
    int t = threadIdx.x;
    int i = c * 256 + t;
    sm[t] = (i < n) ? counts[i] : 0;
    __syncthreads();
    for (int s = 128; s > 0; s >>= 1) {
        if (t < s) sm[t] += sm[t + s];
        __syncthreads();
    }
    if (t == 0) chunkSums[c] = sm[0];
}

__global__ void scan_spine(int* __restrict__ chunkSums, int numChunks, int* __restrict__ row_off, int n) {
    __shared__ int sm[512];
    int t = threadIdx.x;
    int v = (t < numChunks) ? chunkSums[t] : 0;
    sm[t] = v;
    __syncthreads();
    for (int s = 1; s < 512; s <<= 1) {
        int add = (t >= s) ? sm[t - s] : 0;
        __syncthreads();
        sm[t] += add;
        __syncthreads();
    }
    if (t < numChunks) chunkSums[t] = sm[t] - v;   // exclusive: bucket start offsets
    if (t == 511) row_off[n] = sm[511];
}

__global__ void scan_final(const int* __restrict__ counts, const int* __restrict__ chunkSums,
                           int* __restrict__ row_off, int n) {
    __shared__ int sm[256];
    int c = blockIdx.x;
    int t = threadIdx.x;
    int i = c * 256 + t;
    int v = (i < n) ? counts[i] : 0;
    sm[t] = v;
    __syncthreads();
    for (int s = 1; s < 256; s <<= 1) {
        int add = (t >= s) ? sm[t - s] : 0;
        __syncthreads();
        sm[t] += add;
        __syncthreads();
    }
    if (i < n) row_off[i] = chunkSums[c] + sm[t] - v;
}

// ---------------- two-pass bucketed scatter ----------------
// Bucket b = rows [b*256, b*256+256). bucketOff[b] = chunkSums[b] (CSR start of
// the bucket). Pass 1 bins edges into buckets with LDS counting + one global
// atomic per (block,bucket) reservation, appending packed (col<<8|rowLocal, val)
// entries in ~340B consecutive runs (near-full cache-line utilization, vs the
// old 4B-random-scatter that wrote 294MB for 25.6MB of payload).
// Pass 2: one block per bucket reorders its ~65KB segment into per-row CSR
// order; the write window is L2-resident so lines evict full.

__global__ void scatter_pass1(const int* __restrict__ row, const int* __restrict__ col,
                              const float* __restrict__ val,
                              const int* __restrict__ bucketOff, int* __restrict__ gcur,
                              int2* __restrict__ tmpE) {
    __shared__ int cnt[NB];
    __shared__ int base[NB];
    const int t = threadIdx.x;
    const int bs = blockIdx.x * EPB;
    const int be = min(N_EDGES, bs + EPB);
    for (int b = t; b < NB; b += 256) cnt[b] = 0;
    __syncthreads();
    for (int i = bs + t; i < be; i += 256) {
        atomicAdd(&cnt[row[i] >> 8], 1);
    }
    __syncthreads();
    for (int b = t; b < NB; b += 256) {
        int c = cnt[b];
        base[b] = bucketOff[b] + (c ? atomicAdd(&gcur[b], c) : 0);
        cnt[b] = 0;
    }
    __syncthreads();
    for (int i = bs + t; i < be; i += 256) {
        int r = row[i];
        int b = r >> 8;
        int pos = base[b] + atomicAdd(&cnt[b], 1);
        int2 e;
        e.x = (col[i] << 8) | (r & 255);
        e.y = __float_as_int(val[i]);
        tmpE[pos] = e;
    }
}

__global__ void scatter_pass2(const int2* __restrict__ tmpE, const int* __restrict__ bucketOff,
                              const int* __restrict__ row_off, int2* __restrict__ csr) {
    __shared__ int lcur[256];
    __shared__ int roff[256];
    const int b = blockIdx.x;
    const int t = threadIdx.x;
    const int rowBase = b << 8;
    const int gr = rowBase + t;
    lcur[t] = 0;
    roff[t] = (gr < N_NODES) ? row_off[gr] : 0;
    __syncthreads();
    const int segStart = bucketOff[b];
    const int segEnd = (b == NB - 1) ? N_EDGES : bucketOff[b + 1];
    for (int i = segStart + t; i < segEnd; i += 256) {
        int2 e = tmpE[i];
        int rl = e.x & 255;
        int pos = roff[rl] + atomicAdd(&lcur[rl], 1);
        int2 o;
        o.x = e.x >> 8;          // e.x < 2^25, positive
        o.y = e.y;
        csr[pos] = o;
    }
}

// ---------------- convert x -> bf16 segment of Ab ----------------

__global__ void convert_x(const float* __restrict__ x, ushort* __restrict__ Ab) {
    int gid = blockIdx.x * blockDim.x + threadIdx.x;       // one per 4 elems
    if (gid >= N_NODES * F_IN / 4) return;
    int li = gid * 4;
    int node = li >> 8;
    int c = li & 255;
    float4 v = *reinterpret_cast<const float4*>(&x[li]);
    ushort4 o;
    o.x = f2b(v.x); o.y = f2b(v.y); o.z = f2b(v.z); o.w = f2b(v.w);
    *reinterpret_cast<ushort4*>(&Ab[(size_t)node * K_TOT + c]) = o;
}

// ---------------- SpMM (bf16 in, bf16 out, fp32 accumulate) ----------------
// one wave per row; lane handles 4 consecutive features (ushort4 = 8 B).
// 8-deep gather pipeline, dual FMA chains. CSR is packed int2 (col, val_bits).

__global__ void spmm_bf16(const int* __restrict__ row_off, const int2* __restrict__ csr,
                          const ushort* __restrict__ h, int hs,
                          ushort* __restrict__ y, int ys) {
    int wave = threadIdx.x >> 6;
    int lane = threadIdx.x & 63;
    int row = blockIdx.x * 4 + wave;
    if (row >= N_NODES) return;
    int s = row_off[row];
    int e = row_off[row + 1];
    const size_t loff = (size_t)lane * 4;

    float ax0 = 0.f, ay0 = 0.f, az0 = 0.f, aw0 = 0.f;
    float ax1 = 0.f, ay1 = 0.f, az1 = 0.f, aw1 = 0.f;

    int j = s;
    for (; j + 8 <= e; j += 8) {
        int2 ev[8];
#pragma unroll
        for (int u = 0; u < 8; u++) ev[u] = csr[j + u];
        ushort4 g[8];
#pragma unroll
        for (int u = 0; u < 8; u++)
            g[u] = *reinterpret_cast<const ushort4*>(&h[(size_t)ev[u].x * hs + loff]);
#pragma unroll
        for (int u = 0; u < 8; u += 2) {
            float v0 = __int_as_float(ev[u].y);
            float v1 = __int_as_float(ev[u + 1].y);
            ax0 += v0 * b2f(g[u].x);
            ay0 += v0 * b2f(g[u].y);
            az0 += v0 * b2f(g[u].z);
            aw0 += v0 * b2f(g[u].w);
            ax1 += v1 * b2f(g[u + 1].x);
            ay1 += v1 * b2f(g[u + 1].y);
            az1 += v1 * b2f(g[u + 1].z);
            aw1 += v1 * b2f(g[u + 1].w);
        }
    }
    for (; j < e; j++) {
        int2 ev = csr[j];
        float v = __int_as_float(ev.y);
        ushort4 hv = *reinterpret_cast<const ushort4*>(&h[(size_t)ev.x * hs + loff]);
        ax0 += v * b2f(hv.x);
        ay0 += v * b2f(hv.y);
        az0 += v * b2f(hv.z);
        aw0 += v * b2f(hv.w);
    }
    ushort4 o;
    o.x = f2b(ax0 + ax1);
    o.y = f2b(ay0 + ay1);
    o.z = f2b(az0 + az1);
    o.w = f2b(aw0 + aw1);
    *reinterpret_cast<ushort4*>(&y[(size_t)row * ys + lane * 4]) = o;
}

// ---------------- weight / BN prep ----------------
// Wt: bf16, K-major: Wt[n][kg], n in 0..511, kg in 0..1023
// kg seg 0 = sum_j w{a,b}_x[j]; seg s=1..3 = w{a,b}_adj[s-1]

__global__ void build_weights_t(const float* __restrict__ wa_x, const float* __restrict__ wa_adj,
                                const float* __restrict__ wb_x, const float* __restrict__ wb_adj,
                                ushort* __restrict__ Wt) {
    int idx = blockIdx.x * blockDim.x + threadIdx.x;
    if (idx >= M_OUT * K_TOT) return;
    int n = idx >> 10;        // 0..511
    int kg = idx & 1023;      // 0..1023
    int seg = kg >> 8;
    int k = kg & 255;
    float w;
    if (seg == 0) {
        if (n < 256)
            w = wa_x[0 * 65536 + k * 256 + n] + wa_x[1 * 65536 + k * 256 + n] + wa_x[2 * 65536 + k * 256 + n];
        else {
            int nn = n - 256;
            w = wb_x[0 * 65536 + k * 256 + nn] + wb_x[1 * 65536 + k * 256 + nn] + wb_x[2 * 65536 + k * 256 + nn];
        }
    } else {
        int s = seg - 1;
        if (n < 256) w = wa_adj[s * 65536 + k * 256 + n];
        else         w = wb_adj[s * 65536 + k * 256 + (n - 256)];
    }
    Wt[idx] = f2b(w);
}

__global__ void build_bn(const float* __restrict__ ga, const float* __restrict__ ba,
                         const float* __restrict__ ma, const float* __restrict__ va,
                         const float* __restrict__ gb, const float* __restrict__ bb,
                         const float* __restrict__ mb, const float* __restrict__ vb,
                         float* __restrict__ scale, float* __restrict__ bias) {
    int c = blockIdx.x * blockDim.x + threadIdx.x;
    if (c >= 512) return;
    float g, b, m, v;
    if (c < 256) { g = ga[c]; b = ba[c]; m = ma[c]; v = va[c]; }
    else { int cc = c - 256; g = gb[cc]; b = bb[cc]; m = mb[cc]; v = vb[cc]; }
    float s = g / sqrtf(v + EPS_BN);
    scale[c] = s;
    bias[c] = b - m * s;
}

// ---------------- MFMA GEMM: C[N,512] = Ab[N,1024] @ Wt^T, fused relu+BN ----------------
// block = 256 threads = 4 waves (2x2), block tile 128x128, wave tile 64x64
// Ab row-major [m][k]; Wt K-major [n][k]  =>  both staged identically.
// LDS stride 40 elems (80 B): rows hit banks with period 8 -> 2-way (free).

#define LDS_STRIDE 40

__global__ void gemm_mfma(const ushort* __restrict__ Ab, const ushort* __restrict__ Wt,
                          float* __restrict__ C,
                          const float* __restrict__ scale, const float* __restrict__ bias) {
    __shared__ ushort As[128 * LDS_STRIDE];
    __shared__ ushort Bs[128 * LDS_STRIDE];
    const int tid = threadIdx.x;
    const int lane = tid & 63;
    const int wave = tid >> 6;
    const int wm = wave >> 1;       // wave row half (0/1)
    const int wn = wave & 1;        // wave col half (0/1)
    const int quad = lane >> 4;
    const int l16 = lane & 15;
    const int mBase = blockIdx.y * 128;
    const int nBase = blockIdx.x * 128;

    floatx4 acc[4][4];
#pragma unroll
    for (int i = 0; i < 4; i++)
#pragma unroll
        for (int j = 0; j < 4; j++) acc[i][j] = (floatx4){0.f, 0.f, 0.f, 0.f};

    for (int k0 = 0; k0 < K_TOT; k0 += 32) {
        // stage A and B tiles: 128 rows x 32 cols bf16 each
#pragma unroll
        for (int p = 0; p < 2; p++) {
            int li = tid + p * 256;
            int row = li >> 2;             // 0..127
            int c8 = (li & 3) * 8;         // 0,8,16,24
            int gm = mBase + row; if (gm > N_NODES - 1) gm = N_NODES - 1;
            uint4 va = *reinterpret_cast<const uint4*>(&Ab[(size_t)gm * K_TOT + k0 + c8]);
            uint4 vb = *reinterpret_cast<const uint4*>(&Wt[(size_t)(nBase + row) * K_TOT + k0 + c8]);
            *reinterpret_cast<uint4*>(&As[row * LDS_STRIDE + c8]) = va;
            *reinterpret_cast<uint4*>(&Bs[row * LDS_STRIDE + c8]) = vb;
        }
        __syncthreads();

        short8 a_frag[4], b_frag[4];
#pragma unroll
        for (int i = 0; i < 4; i++)
            a_frag[i] = *reinterpret_cast<const short8*>(&As[(wm * 64 + i * 16 + l16) * LDS_STRIDE + quad * 8]);
#pragma unroll
        for (int j = 0; j < 4; j++)
            b_frag[j] = *reinterpret_cast<const short8*>(&Bs[(wn * 64 + j * 16 + l16) * LDS_STRIDE + quad * 8]);
#pragma unroll
        for (int i = 0; i < 4; i++)
#pragma unroll
            for (int j = 0; j < 4; j++)
                acc[i][j] = __builtin_amdgcn_mfma_f32_16x16x32_bf16(a_frag[i], b_frag[j], acc[i][j], 0, 0, 0);
        __syncthreads();
    }

    // epilogue: relu on cols < 256, then BN affine; C row-major [m][512]
    float sc[4], bs[4];
    int gncol[4];
#pragma unroll
    for (int j = 0; j < 4; j++) {
        int gn = nBase + wn * 64 + j * 16 + l16;
        gncol[j] = gn;
        sc[j] = scale[gn];
        bs[j] = bias[gn];
    }
#pragma unroll
    for (int i = 0; i < 4; i++) {
#pragma unroll
        for (int r = 0; r < 4; r++) {
            int gm = mBase + wm * 64 + i * 16 + quad * 4 + r;
            if (gm >= N_NODES) continue;
#pragma unroll
            for (int j = 0; j < 4; j++) {
                float v = acc[i][j][r];
                if (gncol[j] < 256) v = fmaxf(v, 0.f);
                v = v * sc[j] + bs[j];
                C[(size_t)gm * M_OUT + gncol[j]] = v;
            }
        }
    }
}

// ---------------- launch ----------------

static inline size_t align_up(size_t x, size_t a) { return (x + a - 1) & ~(a - 1); }

extern "C" void kernel_launch(void* const* d_in, const int* in_sizes, int n_in,
                              void* d_out, int out_size, void* d_ws, size_t ws_size,
                              hipStream_t stream) {
    const float* x      = (const float*)d_in[0];
    const int*   erow   = (const int*)d_in[1];
    const int*   ecol   = (const int*)d_in[2];
    const float* eval   = (const float*)d_in[3];
    const float* wa_x   = (const float*)d_in[4];
    const float* wa_adj = (const float*)d_in[5];
    const float* wb_x   = (const float*)d_in[6];
    const float* wb_adj = (const float*)d_in[7];
    const float* ga = (const float*)d_in[8];
    const float* ba = (const float*)d_in[9];
    const float* ma = (const float*)d_in[10];
    const float* va = (const float*)d_in[11];
    const float* gb = (const float*)d_in[12];
    const float* bb = (const float*)d_in[13];
    const float* mb = (const float*)d_in[14];
    const float* vb = (const float*)d_in[15];
    float* out = (float*)d_out;

    char* ws = (char*)d_ws;
    size_t off = 0;
    int*    row_off   = (int*)(ws + off);    off = align_up(off + (size_t)(N_NODES + 1) * 4, 1024);
    int*    cursor    = (int*)(ws + off);    off = align_up(off + (size_t)N_NODES * 4, 1024);
    int*    chunkSums = (int*)(ws + off);    off = align_up(off + (size_t)NUM_CHUNKS * 4, 1024);
    int2*   csr       = (int2*)(ws + off);   off = align_up(off + (size_t)N_EDGES * 8, 1024);
    ushort* Wt        = (ushort*)(ws + off); off = align_up(off + (size_t)M_OUT * K_TOT * 2, 1024);
    float*  scale     = (float*)(ws + off);  off = align_up(off + 512 * 4, 1024);
    float*  bias      = (float*)(ws + off);  off = align_up(off + 512 * 4, 1024);
    ushort* Ab        = (ushort*)(ws + off); off = align_up(off + (size_t)N_NODES * K_TOT * 2, 1024);
    ushort* tmp       = (ushort*)(ws + off); off = align_up(off + (size_t)N_NODES * F_IN * 2, 1024);
    // pass-1 temp edge buffer aliases the hop scratch (stream-serial: pass1/pass2
    // complete before the spmm chain touches tmp). 25.6MB <= 51.2MB.
    int2*   tmpE      = (int2*)tmp;
    (void)ws_size; (void)in_sizes; (void)n_in; (void)out_size;

    const int zeroBlocks = (N_NODES + 255) / 256;
    const int edgeBlocks = (N_EDGES + 255) / 256;
    const int p1Blocks = (N_EDGES + EPB - 1) / EPB;

    // ---- CSR build ----
    zero_i32<<<zeroBlocks, 256, 0, stream>>>(cursor, N_NODES);
    hist_kernel<<<edgeBlocks, 256, 0, stream>>>(erow, cursor, N_EDGES);
    scan_chunk_sums<<<NUM_CHUNKS, 256, 0, stream>>>(cursor, chunkSums, N_NODES);
    scan_spine<<<1, 512, 0, stream>>>(chunkSums, NUM_CHUNKS, row_off, N_NODES);
    scan_final<<<NUM_CHUNKS, 256, 0, stream>>>(cursor, chunkSums, row_off, N_NODES);
    // reuse cursor[0..NB) as per-bucket global cursors
    zero_i32<<<(NB + 255) / 256, 256, 0, stream>>>(cursor, NB);
    scatter_pass1<<<p1Blocks, 256, 0, stream>>>(erow, ecol, eval, chunkSums, cursor, tmpE);
    scatter_pass2<<<NB, 256, 0, stream>>>(tmpE, chunkSums, row_off, csr);

    // ---- weight & BN prep ----
    build_weights_t<<<(M_OUT * K_TOT) / 256, 256, 0, stream>>>(wa_x, wa_adj, wb_x, wb_adj, Wt);
    build_bn<<<2, 256, 0, stream>>>(ga, ba, ma, va, gb, bb, mb, vb, scale, bias);

    // ---- x -> bf16 (segment 0 of Ab) ----
    convert_x<<<(N_NODES * F_IN / 4 + 255) / 256, 256, 0, stream>>>(x, Ab);

    // ---- hop chain (bf16 storage, fp32 accumulate) ----
    const int spmmBlocks = (N_NODES + 3) / 4;
    spmm_bf16<<<spmmBlocks, 256, 0, stream>>>(row_off, csr,
                                              Ab + 0 * 256, K_TOT, Ab + 1 * 256, K_TOT);   // A x
    spmm_bf16<<<spmmBlocks, 256, 0, stream>>>(row_off, csr,
                                              Ab + 1 * 256, K_TOT, Ab + 2 * 256, K_TOT);   // A^2 x
    spmm_bf16<<<spmmBlocks, 256, 0, stream>>>(row_off, csr,
                                              Ab + 2 * 256, K_TOT, tmp, F_IN);             // A^3 x
    spmm_bf16<<<spmmBlocks, 256, 0, stream>>>(row_off, csr,
                                              tmp, F_IN, Ab + 3 * 256, K_TOT);             // A^4 x

    // ---- fused GEMM + relu + BN ----
    dim3 gemmGrid(M_OUT / 128, (N_NODES + 127) / 128);
    gemm_mfma<<<gemmGrid, 256, 0, stream>>>(Ab, Wt, out, scale, bias);
}